// Round 9
// baseline (197.437 us; speedup 1.0000x reference)
//
#include <hip/hip_runtime.h>
#include <cmath>

// Problem constants (fixed by the reference).
constexpr int B  = 4096;
constexpr int D  = 768;
constexpr int P  = 96;
constexpr int C  = 256;
constexpr int SD = 8;    // D / P

typedef __attribute__((ext_vector_type(8))) short  short8;   // 8 bf16 (4 VGPR)
typedef __attribute__((ext_vector_type(4))) float  floatx4;  // MFMA acc

// fp32 -> bf16 RNE (bit-level, no header API dependence)
__device__ __forceinline__ unsigned short f2bf(float f) {
    unsigned u = __float_as_uint(f);
    u += 0x7FFFu + ((u >> 16) & 1u);
    return (unsigned short)(u >> 16);
}
__device__ __forceinline__ float bf2f(unsigned short s) {
    return __uint_as_float(((unsigned)s) << 16);
}

// ---- numpy fp32 emulation helpers (exact path, validated absmax=0) ---------
__device__ __forceinline__ float tree8(float q0, float q1, float q2, float q3,
                                       float q4, float q5, float q6, float q7)
{
#pragma clang fp contract(off)
    return ((q0 + q1) + (q2 + q3)) + ((q4 + q5) + (q6 + q7));
}

__device__ __forceinline__ float proba_np(const float* __restrict__ cbf,
                                          const float* __restrict__ csq,
                                          int c, float4 va, float4 vb, float vsq)
{
#pragma clang fp contract(off)
    float4 ca = ((const float4*)cbf)[2 * c];
    float4 cb = ((const float4*)cbf)[2 * c + 1];
    float p0 = va.x * ca.x, p1 = va.y * ca.y, p2 = va.z * ca.z, p3 = va.w * ca.w;
    float p4 = vb.x * cb.x, p5 = vb.y * cb.y, p6 = vb.z * cb.z, p7 = vb.w * cb.w;
    float l0 = p0 + p4, l1 = p1 + p5, l2 = p2 + p6, l3 = p3 + p7;
    float vc = (l0 + l2) + (l1 + l3);
    float tt = vsq - 2.0f * vc;
    float u  = tt + csq[c];
    return -u;
}

// Exact numpy-order argmax incl. softmax tie path (validated rounds 1-8).
__device__ __attribute__((noinline))
int exact_search(const float* __restrict__ cbf, const float* __restrict__ csq,
                 float4 va, float4 vb, float vsq)
{
#pragma clang fp contract(off)
    float best = -3.402823466e38f, second = -3.402823466e38f;
    int bi = 0;
    for (int c = 0; c < C; ++c) {
        float pr = proba_np(cbf, csq, c, va, vb, vsq);
        if (pr > best)        { second = best; best = pr; bi = c; }
        else if (pr > second) { second = pr; }
    }
    int idx = bi;

    if (best - second <= 1.0e-6f) {
        float m = best;
        float r0[8] = {0,0,0,0,0,0,0,0};
        float r1[8] = {0,0,0,0,0,0,0,0};
        for (int cg = 0; cg < 16; ++cg) {
            #pragma unroll
            for (int j = 0; j < 8; ++j) {
                float pr = proba_np(cbf, csq, cg * 8 + j, va, vb, vsq);
                r0[j] += expf(pr - m);
            }
        }
        for (int cg = 16; cg < 32; ++cg) {
            #pragma unroll
            for (int j = 0; j < 8; ++j) {
                float pr = proba_np(cbf, csq, cg * 8 + j, va, vb, vsq);
                r1[j] += expf(pr - m);
            }
        }
        float sum = tree8(r0[0],r0[1],r0[2],r0[3],r0[4],r0[5],r0[6],r0[7])
                  + tree8(r1[0],r1[1],r1[2],r1[3],r1[4],r1[5],r1[6],r1[7]);
        float abest = -1.0f;
        int   ai    = 0;
        for (int c = 0; c < C; ++c) {
            float pr = proba_np(cbf, csq, c, va, vb, vsq);
            float e  = expf(pr - m);
            float a  = e / sum;
            if (a > abest) { abest = a; ai = c; }
        }
        idx = ai;
    }
    return idx;
}

// MFMA scoring kernel.
// Block = 4 waves; wave w handles rows [(by*4+w)*16, +16) x partition bx.
// One mfma_f32_16x16x32_bf16 per 16-centroid tile computes the full
// split-precision dot: A-k = [vhi,vlo,vhi,vlo], B-k = [chi,clo,clo,chi]
// => sum = (vhi+vlo)(chi+clo) ~ v.c with |err| <~ 3.5e-5 worst-case.
// Acc is initialized to -0.5*||c||^2, so acc_out = s' = v.c - 0.5*csq.
// Rows with top-2 gap <= 2e-4 (in s' units; >=3x worst-case error margin)
// are re-run through the validated exact numpy path.
// C/D layout: col = lane&15, row = (lane>>4)*4 + reg  [m89-verified]
// A layout:   A[m = lane&15][k = (lane>>4)*8 + j]
// B layout:   B[k = (lane>>4)*8 + j][n = lane&15]
__global__ __launch_bounds__(256, 4)
void pq_mfma_kernel(const float* __restrict__ vecs,
                    const float* __restrict__ codebook,
                    float* __restrict__ out)
{
    __shared__ float  cbf [C * SD];  // 8 KB fp32 codebook (exact path + gather)
    __shared__ float  csqn[C];       // 1 KB numpy-order ||c||^2 (exact path)
    __shared__ float  csqh[C];       // 1 KB -0.5*csq (acc seed)
    __shared__ short8 cbh [C];       // 4 KB bf16 hi split
    __shared__ short8 cbl [C];       // 4 KB bf16 lo split

    const int p = blockIdx.x;                  // 0..95
    const int t = threadIdx.x;                 // 0..255
    const int w = t >> 6;                      // wave id 0..3
    const int l = t & 63;                      // lane
    const int n = l & 15;                      // col-in-tile / A-row
    const int q = l >> 4;                      // quad 0..3
    const int rowbase = (blockIdx.y * 4 + w) * 16;

    // ---- stage codebook[p] fp32: 512 float4, 2 per thread ----
    const float4* src = (const float4*)(codebook + (size_t)p * C * SD);
    ((float4*)cbf)[t]       = src[t];
    ((float4*)cbf)[t + 256] = src[t + 256];
    __syncthreads();

    // ---- per-centroid (1/thread): csq (numpy order), seed, bf16 hi/lo ----
    {
        const float* cc = cbf + t * SD;
        float q0 = cc[0]*cc[0], q1 = cc[1]*cc[1], q2 = cc[2]*cc[2], q3 = cc[3]*cc[3];
        float q4 = cc[4]*cc[4], q5 = cc[5]*cc[5], q6 = cc[6]*cc[6], q7 = cc[7]*cc[7];
        float s = tree8(q0,q1,q2,q3,q4,q5,q6,q7);
        csqn[t] = s;
        csqh[t] = -0.5f * s;
        unsigned short* hh = (unsigned short*)&cbh[t];
        unsigned short* ll = (unsigned short*)&cbl[t];
        #pragma unroll
        for (int j = 0; j < SD; ++j) {
            unsigned short hi = f2bf(cc[j]);
            hh[j] = hi;
            ll[j] = f2bf(cc[j] - bf2f(hi));
        }
    }
    __syncthreads();

    // ---- A fragment: lane holds row m = n of the tile, k = q*8 + j ----
    // k-groups: [vhi, vlo, vhi, vlo] -> quads 0,2 take hi; 1,3 take lo.
    short8 afrag;
    {
        const float* vp = vecs + (size_t)(rowbase + n) * D + (size_t)p * SD;
        float4 v0 = ((const float4*)vp)[0];
        float4 v1 = ((const float4*)vp)[1];
        float vf[8] = { v0.x, v0.y, v0.z, v0.w, v1.x, v1.y, v1.z, v1.w };
        const bool hiA = ((q & 1) == 0);
        #pragma unroll
        for (int j = 0; j < SD; ++j) {
            unsigned short hi = f2bf(vf[j]);
            unsigned short lo = f2bf(vf[j] - bf2f(hi));
            ((unsigned short*)&afrag)[j] = (short)(hiA ? hi : lo);
        }
    }
    // B k-groups: [chi, clo, clo, chi] -> quads 0,3 read hi; 1,2 read lo.
    const short8* Bsrc = (q == 0 || q == 3) ? cbh : cbl;

    // ---- 16 tiles of 16 centroids: 1 MFMA each; per-lane top-2 over tiles ----
    float best[4]   = { -3.402823466e38f, -3.402823466e38f,
                        -3.402823466e38f, -3.402823466e38f };
    float second[4] = { -3.402823466e38f, -3.402823466e38f,
                        -3.402823466e38f, -3.402823466e38f };
    int   idx[4]    = { 0, 0, 0, 0 };

    for (int tt = 0; tt < 16; ++tt) {
        const int c = tt * 16 + n;             // this lane's centroid column
        float h = csqh[c];
        floatx4 acc = { h, h, h, h };
        short8 bfrag = Bsrc[c];
        acc = __builtin_amdgcn_mfma_f32_16x16x32_bf16(afrag, bfrag, acc, 0, 0, 0);
        #pragma unroll
        for (int r = 0; r < 4; ++r) {          // rows q*4 + r
            float s = acc[r];
            bool gt = s > best[r];
            second[r] = fmaxf(second[r], fminf(s, best[r]));
            idx[r]    = gt ? c : idx[r];
            best[r]   = fmaxf(s, best[r]);
        }
    }

    // ---- cross-lane merge over the 16 cols (lanes of the same quad) ----
    #pragma unroll
    for (int m = 1; m < 16; m <<= 1) {
        #pragma unroll
        for (int r = 0; r < 4; ++r) {
            float ob = __shfl_xor(best[r],   m, 64);
            float os = __shfl_xor(second[r], m, 64);
            int   oi = __shfl_xor(idx[r],    m, 64);
            bool better = (ob > best[r]) || (ob == best[r] && oi < idx[r]);
            second[r] = fmaxf(fmaxf(second[r], os), fminf(ob, best[r]));
            idx[r]    = better ? oi : idx[r];
            best[r]   = fmaxf(best[r], ob);
        }
    }

    // ---- resolve + store: lane n<4 of each quad owns row q*4 + n ----
    if (n < 4) {
        const int r   = n;
        const int row = rowbase + q * 4 + n;
        int id = idx[r];
        if (best[r] - second[r] <= 2.0e-4f) {  // near-tie: exact numpy path
            const float* vp = vecs + (size_t)row * D + (size_t)p * SD;
            float4 xa = ((const float4*)vp)[0];
            float4 xb = ((const float4*)vp)[1];
            float q0 = xa.x*xa.x, q1 = xa.y*xa.y, q2 = xa.z*xa.z, q3 = xa.w*xa.w;
            float q4 = xb.x*xb.x, q5 = xb.y*xb.y, q6 = xb.z*xb.z, q7 = xb.w*xb.w;
            float vsq = tree8(q0,q1,q2,q3,q4,q5,q6,q7);
            id = exact_search(cbf, csqn, xa, xb, vsq);
        }
        float4 o0 = ((const float4*)cbf)[2 * id];
        float4 o1 = ((const float4*)cbf)[2 * id + 1];
        float4* op = (float4*)(out + (size_t)row * D + (size_t)p * SD);
        op[0] = o0;
        op[1] = o1;
    }
}

extern "C" void kernel_launch(void* const* d_in, const int* in_sizes, int n_in,
                              void* d_out, int out_size, void* d_ws, size_t ws_size,
                              hipStream_t stream)
{
    const float* vecs     = (const float*)d_in[0];  // [B, D] fp32
    const float* codebook = (const float*)d_in[1];  // [P, C, SD] fp32
    float*       out      = (float*)d_out;          // [B, D] fp32

    dim3 grid(P, B / 64);    // (96, 64) = 6144 blocks x 4 waves
    dim3 block(256);
    pq_mfma_kernel<<<grid, block, 0, stream>>>(vecs, codebook, out);
}